// Round 3
// baseline (4567.342 us; speedup 1.0000x reference)
//
#include <hip/hip_runtime.h>
#include <cstdint>
#include <cstddef>

typedef __attribute__((ext_vector_type(8))) short short8;
typedef __attribute__((ext_vector_type(4))) short short4v;
typedef __attribute__((ext_vector_type(4))) float float4v;

typedef __attribute__((address_space(3))) uint32_t lds_u32;
typedef const __attribute__((address_space(1))) uint32_t gl_u32;

__device__ __forceinline__ short f2bf(float f) {
    union { float f; uint32_t u; } v; v.f = f;
    uint32_t r = v.u + 0x7fffu + ((v.u >> 16) & 1u);
    return (short)(r >> 16);
}
__device__ __forceinline__ float u2f(uint32_t u) {
    union { uint32_t u; float f; } v; v.u = u; return v.f;
}
// pack two floats to bf16 pair (round-half-up), lo|hi<<16
__device__ __forceinline__ uint32_t pack2(float lo, float hi) {
    union { float f; uint32_t u; } a, b; a.f = lo; b.f = hi;
    return ((a.u + 0x8000u) >> 16) | ((b.u + 0x8000u) & 0xffff0000u);
}
__device__ __forceinline__ float sigmoidf_(float z) {
    return 1.0f / (1.0f + __expf(-z));
}

// ---------------------------------------------------------------------------
// Prep: x (32768x1024 f32) -> bf16 into Xcat[:, 0:1024] (row stride 1280)
// ---------------------------------------------------------------------------
__global__ __launch_bounds__(256) void xconvert_kernel(const float* __restrict__ x,
                                                       short* __restrict__ Xcat) {
    size_t i = ((size_t)blockIdx.x * 256 + threadIdx.x) * 4;
    size_t r = i >> 10, c = i & 1023;
    float4v v = *(const float4v*)(x + i);
    short4v o;
#pragma unroll
    for (int j = 0; j < 4; ++j) o[j] = f2bf(v[j]);
    *(short4v*)(Xcat + r * 1280 + c) = o;
}

// ---------------------------------------------------------------------------
// Prep: W3b = bf16([Wi; Wf[:, :1024]; Wu[:, :1024]]) (768x1024), Wob = bf16(Wo)
// ---------------------------------------------------------------------------
__global__ __launch_bounds__(256) void wconvert_kernel(const float* __restrict__ Wi,
                                                       const float* __restrict__ Wf,
                                                       const float* __restrict__ Wu,
                                                       const float* __restrict__ Wo,
                                                       short* __restrict__ W3b,
                                                       short* __restrict__ Wob) {
    int i = blockIdx.x * 256 + threadIdx.x;
    if (i < 768 * 1024) {
        int n = i >> 10, k = i & 1023;
        const float* src = (n < 256) ? (Wi + (size_t)n * 1024 + k)
                         : (n < 512) ? (Wf + (size_t)(n - 256) * 1280 + k)
                                     : (Wu + (size_t)(n - 512) * 1280 + k);
        W3b[i] = f2bf(*src);
    } else {
        int j = i - 768 * 1024;
        Wob[j] = f2bf(Wo[j]);
    }
}

// ---------------------------------------------------------------------------
// Tiled bf16 MFMA GEMM: C[gr][gc] = sum_k A[gr][k]*B[gc][k]
// EPI=1: bias + silu(first 256 cols); xm -> xmArr[t][b][256]; xf/xu logits
//        packed into scan-order buffer xfu (dwords: lo=f-gate, hi=u-gate)
// EPI=2: + bo[gc] + x residual, fp32 out
// ---------------------------------------------------------------------------
template <int EPI>
__global__ __launch_bounds__(256) void gemm_bt(const short* __restrict__ A,
                                               const short* __restrict__ Bmat,
                                               const int K, const int lda,
                                               const float* __restrict__ bias1,
                                               const float* __restrict__ bias2,
                                               const float* __restrict__ bias3,
                                               const float* __restrict__ xres,
                                               float* __restrict__ outf,
                                               short* __restrict__ outb,
                                               short* __restrict__ outm) {
    __shared__ __align__(16) short As[4096];
    __shared__ __align__(16) short Bs[4096];

    const int tid = threadIdx.x;
    const int lane = tid & 63;
    const int wv = tid >> 6;
    const int wm = wv >> 1, wn = wv & 1;
    const int row15 = lane & 15;
    const int q = lane >> 4;
    const int tileM = blockIdx.x * 128;
    const int tileN = blockIdx.y * 128;

    float4v acc[4][4];
#pragma unroll
    for (int i = 0; i < 4; ++i)
#pragma unroll
        for (int j = 0; j < 4; ++j) acc[i][j] = {0.f, 0.f, 0.f, 0.f};

    const short* aG = A + (size_t)(tileM + (tid >> 2)) * lda + (tid & 3) * 8;
    const short* bG = Bmat + (size_t)(tileN + (tid >> 2)) * K + (tid & 3) * 8;
    const size_t aStep = (size_t)64 * lda;
    const size_t bStep = (size_t)64 * K;

    lds_u32* AsL = (lds_u32*)As;
    lds_u32* BsL = (lds_u32*)Bs;
    const int base1 = wv * 256;
    const int base2 = 1024 + wv * 256;

    for (int kt = 0; kt < K; kt += 32) {
        __builtin_amdgcn_global_load_lds((gl_u32*)aG,           AsL + base1, 16, 0, 0);
        __builtin_amdgcn_global_load_lds((gl_u32*)(aG + aStep), AsL + base2, 16, 0, 0);
        __builtin_amdgcn_global_load_lds((gl_u32*)bG,           BsL + base1, 16, 0, 0);
        __builtin_amdgcn_global_load_lds((gl_u32*)(bG + bStep), BsL + base2, 16, 0, 0);
        aG += 32; bG += 32;
        __syncthreads();

        short8 af[4], bf8[4];
#pragma unroll
        for (int mt = 0; mt < 4; ++mt)
            af[mt] = *(const short8*)(As + (wm * 64 + mt * 16 + row15) * 32 + q * 8);
#pragma unroll
        for (int nt = 0; nt < 4; ++nt)
            bf8[nt] = *(const short8*)(Bs + (wn * 64 + nt * 16 + row15) * 32 + q * 8);
#pragma unroll
        for (int mt = 0; mt < 4; ++mt)
#pragma unroll
            for (int nt = 0; nt < 4; ++nt)
                acc[mt][nt] = __builtin_amdgcn_mfma_f32_16x16x32_bf16(af[mt], bf8[nt], acc[mt][nt], 0, 0, 0);
        __syncthreads();
    }

#pragma unroll
    for (int mt = 0; mt < 4; ++mt) {
#pragma unroll
        for (int nt = 0; nt < 4; ++nt) {
#pragma unroll
            for (int r = 0; r < 4; ++r) {
                const int gr = tileM + wm * 64 + mt * 16 + q * 4 + r;
                const int gc = tileN + wn * 64 + nt * 16 + row15;
                float v = acc[mt][nt][r];
                if (EPI == 1) {
                    const int b = gr >> 11, t = gr & 2047;
                    if (gc < 256) {
                        float z = v + bias1[gc];
                        z = z * sigmoidf_(z);     // silu
                        outm[((size_t)t * 16 + b) * 256 + gc] = f2bf(z);
                    } else {
                        const int g = (gc >= 512) ? 1 : 0;
                        const int n = gc - 256 - g * 256;
                        float z = v + (g ? bias3[n] : bias2[n]);
                        const int ww = n >> 5, ntl = (n >> 4) & 1, r15 = n & 15;
                        const int qq = b >> 2, rr = b & 3;
                        const size_t dw = ((size_t)(t * 8 + ww) * 64 + (qq * 16 + r15)) * 8 + ntl * 4 + rr;
                        outb[dw * 2 + g] = f2bf(z);
                    }
                } else {
                    const size_t idx = (size_t)gr * 1024 + gc;
                    outf[idx] = v + bias1[gc] + xres[idx];
                }
            }
        }
    }
}

// ---------------------------------------------------------------------------
// scan2: 512 threads, 8 waves. Wave w owns cols n in [32w,32w+32), BOTH gates
// (Wf+Wu B-frags in regs). f,u packed bf16 pairs round-trip LDS with rotation
// swizzle; h-owner thread owns h[b][k0..k0+7], writes hb via one swizzled
// ds_write_b128 in A-frag layout; straight-line loop, loads issued at top of
// step t and consumed after the MFMA phase (intra-iteration latency hiding).
// hb granule layout: g(ks,qa,b) = ks*64 + qa*16 + (b^qa), 16B per granule.
// fu dword layout:   FU(b,k) = b*256 + ((k + 4b)&255).
// ---------------------------------------------------------------------------
__global__ __launch_bounds__(512) void scan2_kernel(const float* __restrict__ Wfp,
                                                    const float* __restrict__ Wup,
                                                    const uint32_t* __restrict__ xfu,
                                                    const short* __restrict__ xmArr,
                                                    short* __restrict__ Xcat,
                                                    float* __restrict__ hfinal) {
    __shared__ __align__(16) short hb[4096];      // 8 KB, A-frag layout (swizzled)
    __shared__ __align__(16) uint32_t fu[4096];   // 16 KB, (f,u) bf16 pairs

    const int tid = threadIdx.x;
    const int lane = tid & 63;
    const int w = tid >> 6;
    const int row15 = lane & 15;
    const int q = lane >> 4;

    // h-owner mapping: thread owns h[b=hb_][k = hk0 .. hk0+7]
    const int hb_ = tid >> 5;
    const int hk0 = (tid & 31) * 8;
    const int hks = hk0 >> 5;
    const int hqa = (hk0 >> 3) & 3;
    const int hgran = hks * 64 + hqa * 16 + (hb_ ^ hqa);
    const int fub1 = hb_ * 256 + ((hk0 + 4 * hb_) & 255);
    const int fub2 = hb_ * 256 + ((hk0 + 4 + 4 * hb_) & 255);

    for (int i = tid; i < 4096; i += 512) hb[i] = 0;

    // B-fragments for both gates, all 8 K-slices, 2 N-blocks (128 VGPRs)
    short8 bfF[8][2], bfU[8][2];
#pragma unroll
    for (int ks = 0; ks < 8; ++ks)
#pragma unroll
        for (int nt = 0; nt < 2; ++nt) {
            const size_t roff = (size_t)(w * 32 + nt * 16 + row15) * 1280 + 1024 + ks * 32 + q * 8;
            short8 vf, vu;
#pragma unroll
            for (int j = 0; j < 8; ++j) { vf[j] = f2bf(Wfp[roff + j]); vu[j] = f2bf(Wup[roff + j]); }
            bfF[ks][nt] = vf; bfU[ks][nt] = vu;
        }

    float hreg[8];
#pragma unroll
    for (int j = 0; j < 8; ++j) hreg[j] = 0.f;

    const uint32_t* zbase = xfu + ((size_t)w * 64 + lane) * 8;
    const short* xmbase = xmArr + (size_t)hb_ * 256 + hk0;
    short* xcbase = Xcat + (size_t)hb_ * 2048 * 1280 + 1024 + hk0;

    __syncthreads();   // hb zero-init visible

    for (int t = 0; t < 2048; ++t) {
        // issue step-t global loads (consumed after the MFMA phase)
        uint32_t zc[8], xmc[4];
        {
            const uint32_t* zp = zbase + (size_t)t * 4096;
            *(uint4*)&zc[0] = *(const uint4*)(zp);
            *(uint4*)&zc[4] = *(const uint4*)(zp + 4);
            *(uint4*)&xmc[0] = *(const uint4*)(xmbase + (size_t)t * 4096);
        }

        // MFMA phase: logits = h @ W{f,u}H^T for this wave's 32 output cols
        float4v aF0 = {0.f, 0.f, 0.f, 0.f}, aF1 = {0.f, 0.f, 0.f, 0.f};
        float4v aU0 = {0.f, 0.f, 0.f, 0.f}, aU1 = {0.f, 0.f, 0.f, 0.f};
#pragma unroll
        for (int ks = 0; ks < 8; ++ks) {
            const int g = ks * 64 + q * 16 + (row15 ^ q);
            short8 af = *(const short8*)(hb + g * 8);
            aF0 = __builtin_amdgcn_mfma_f32_16x16x32_bf16(af, bfF[ks][0], aF0, 0, 0, 0);
            aF1 = __builtin_amdgcn_mfma_f32_16x16x32_bf16(af, bfF[ks][1], aF1, 0, 0, 0);
            aU0 = __builtin_amdgcn_mfma_f32_16x16x32_bf16(af, bfU[ks][0], aU0, 0, 0, 0);
            aU1 = __builtin_amdgcn_mfma_f32_16x16x32_bf16(af, bfU[ks][1], aU1, 0, 0, 0);
        }

        // sigmoid + pack + fu scatter (rotation swizzle, ~2-way max)
#pragma unroll
        for (int nt = 0; nt < 2; ++nt) {
#pragma unroll
            for (int r = 0; r < 4; ++r) {
                const uint32_t zz = zc[nt * 4 + r];
                const float zf = (nt ? aF1[r] : aF0[r]) + u2f(zz << 16);
                const float zu = (nt ? aU1[r] : aU0[r]) + u2f(zz & 0xffff0000u);
                const float fv = sigmoidf_(zf);
                const float uv = sigmoidf_(zu);
                const int b = q * 4 + r;
                const int k = w * 32 + nt * 16 + row15;
                fu[b * 256 + ((k + 4 * b) & 255)] = pack2(fv, uv);
            }
        }
        __syncthreads();

        // elementwise: h_new = f*h + u*xm; one b128 LDS write + one b128 global
        {
            uint4 d0 = *(const uint4*)(fu + fub1);
            uint4 d1 = *(const uint4*)(fu + fub2);
            uint32_t dd[8] = {d0.x, d0.y, d0.z, d0.w, d1.x, d1.y, d1.z, d1.w};
#pragma unroll
            for (int j = 0; j < 8; ++j) {
                const float fv = u2f(dd[j] << 16);
                const float uv = u2f(dd[j] & 0xffff0000u);
                const uint32_t xw = xmc[j >> 1];
                const float xv = (j & 1) ? u2f(xw & 0xffff0000u) : u2f(xw << 16);
                hreg[j] = fv * hreg[j] + uv * xv;
            }
            uint32_t hpk[4];
#pragma unroll
            for (int i = 0; i < 4; ++i) hpk[i] = pack2(hreg[2 * i], hreg[2 * i + 1]);
            *(uint4*)(hb + hgran * 8) = *(const uint4*)hpk;
            *(uint4*)(xcbase + (size_t)t * 1280) = *(const uint4*)hpk;
        }
        __syncthreads();
    }

#pragma unroll
    for (int j = 0; j < 8; ++j) hfinal[hb_ * 256 + hk0 + j] = hreg[j];
}

// ---------------------------------------------------------------------------
extern "C" void kernel_launch(void* const* d_in, const int* in_sizes, int n_in,
                              void* d_out, int out_size, void* d_ws, size_t ws_size,
                              hipStream_t stream) {
    const float* x  = (const float*)d_in[0];
    const float* Wi = (const float*)d_in[1];
    const float* bi = (const float*)d_in[2];
    const float* Wf = (const float*)d_in[3];
    const float* bf = (const float*)d_in[4];
    const float* Wu = (const float*)d_in[5];
    const float* bu = (const float*)d_in[6];
    const float* Wo = (const float*)d_in[7];
    const float* bo = (const float*)d_in[8];
    float* out = (float*)d_out;   // 33554432 outs + 4096 h_final

    char* ws = (char*)d_ws;
    short*    Xcat  = (short*)ws;                            // 83,886,080 B
    short*    xmArr = (short*)(ws + 83886080ULL);            // 16,777,216 B  [t][b][256] bf16
    uint32_t* xfu   = (uint32_t*)(ws + 100663296ULL);        // 33,554,432 B  [t][w][lane][8] dwords
    short*    W3b   = (short*)(ws + 134217728ULL);           //  1,572,864 B
    short*    Wob   = (short*)(ws + 135790592ULL);           //  2,621,440 B

    xconvert_kernel<<<dim3(32768), dim3(256), 0, stream>>>(x, Xcat);
    wconvert_kernel<<<dim3(8192), dim3(256), 0, stream>>>(Wi, Wf, Wu, Wo, W3b, Wob);
    // xm/xf/xu: (32768 x 768) = Xcat[:, :1024] @ W3b^T (+bias, silu on xm)
    gemm_bt<1><<<dim3(256, 6), dim3(256), 0, stream>>>(Xcat, W3b, 1024, 1280,
                                                       bi, bf, bu, nullptr, nullptr,
                                                       (short*)xfu, xmArr);
    // sequential recurrence (writes H into Xcat[:, 1024:1280) and h_final)
    scan2_kernel<<<dim3(1), dim3(512), 0, stream>>>(Wf, Wu, xfu, xmArr, Xcat, out + 33554432);
    // out = x + Xcat @ Wo^T + bo
    gemm_bt<2><<<dim3(256, 8), dim3(256), 0, stream>>>(Xcat, Wob, 1280, 1280,
                                                       bo, nullptr, nullptr, x, out, nullptr,
                                                       nullptr);
}